// Round 11
// baseline (1249.047 us; speedup 1.0000x reference)
//
#include <hip/hip_runtime.h>

using u16 = unsigned short;
typedef short short8 __attribute__((ext_vector_type(8)));
typedef float f32x4 __attribute__((ext_vector_type(4)));

#define T_TOK 100352

__device__ __forceinline__ float bf2f(u16 u) {
    return __uint_as_float(((unsigned int)u) << 16);
}
__device__ __forceinline__ u16 f2bf(float f) {
    unsigned int u = __float_as_uint(f);
    u += 0x7fffu + ((u >> 16) & 1u);   // round-to-nearest-even
    return (u16)(u >> 16);
}

// async global->LDS, 16B per lane; LDS dest = wave-uniform base + lane*16
__device__ __forceinline__ void ld_g2l16(const u16* g, u16* l) {
    __builtin_amdgcn_global_load_lds((const __attribute__((address_space(1))) void*)g,
                                     (__attribute__((address_space(3))) void*)l,
                                     16, 0, 0);
}

// ---------------------------------------------------------------- setup ----
// all six weight matrices -> bf16 in one launch (contiguous dst arena)
__global__ __launch_bounds__(256) void cvt_all_k(const float* __restrict__ q1,
                                                 const float* __restrict__ q2,
                                                 const float* __restrict__ p1,
                                                 const float* __restrict__ p2,
                                                 const float* __restrict__ f1,
                                                 const float* __restrict__ f2,
                                                 u16* __restrict__ dst) {
    int i = blockIdx.x * 256 + threadIdx.x;
    if (i >= 655360) return;
    const float* s; int off;
    if (i < 49152)       { s = q1; off = 0; }
    else if (i < 98304)  { s = q2; off = 49152; }
    else if (i < 114688) { s = p1; off = 98304; }
    else if (i < 131072) { s = p2; off = 114688; }
    else if (i < 393216) { s = f1; off = 131072; }
    else                 { s = f2; off = 393216; }
    dst[i] = f2bf(s[i - off]);
}

// bias table: [half(2)][wtype(4)][head(4)][n(49)][m(49)] f32
// wtype = (wi==31)*2 + (wj==31)
__global__ __launch_bounds__(256) void bias_tbl_k(const float* __restrict__ rpb0,
                                                  const float* __restrict__ rpb1,
                                                  float* __restrict__ tbl) {
    int id = blockIdx.x;               // half*16 + wtype*4 + h
    int hsel = id >> 4, wtype = (id >> 2) & 3, h = id & 3;
    const float* rpb = hsel ? rpb1 : rpb0;
    int redge = wtype >> 1, cedge = wtype & 1;
    float* o = tbl + (size_t)id * 2401;
    for (int i = threadIdx.x; i < 2401; i += 256) {
        int n = i / 49, m = i - n * 49;
        int rn = n / 7, cn = n - rn * 7, rm = m / 7, cm = m - rm * 7;
        int rpi = (rn - rm + 6) * 13 + (cn - cm + 6);
        float v = rpb[rpi * 4 + h];
        // shifted-window mask (regions only differ on edge windows)
        int grn = redge ? (rn < 4 ? 1 : 2) : 0;
        int grm = redge ? (rm < 4 ? 1 : 2) : 0;
        int gcn = cedge ? (cn < 4 ? 1 : 2) : 0;
        int gcm = cedge ? (cm < 4 ? 1 : 2) : 0;
        if ((grn * 3 + gcn) != (grm * 3 + gcm)) v += -100.0f;
        // physical cone mask (derived allowed sets, fp32-borderline (5,6) IN)
        int dr = rn - rm, dc = cn - cm;
        bool ok;
        if (n == m) ok = true;
        else if (hsel == 0)
            ok = (dc == 1 && dr == 1) || (dc == 2 && dr == 2) ||
                 (dc == 3 && (dr == 3 || dr == 4)) ||
                 (dc == 4 && (dr == 4 || dr == 5)) ||
                 (dc == 5 && (dr == 5 || dr == 6)) ||
                 (dc == 6 && (dr == 5 || dr == 6));
        else
            ok = (dr == -1 && dc >= 3 && dc <= 6) || (dr == -2 && dc == 6);
        if (!ok) v += -100.0f;
        o[i] = v;
    }
}

// ------------------------------------------------------------ layernorms ----
// LN1 + roll(-3,-3) + window partition -> bf16 windowed layout, both halves
__global__ __launch_bounds__(256) void ln1_k(const float* __restrict__ x,
                                             const float* __restrict__ g,
                                             const float* __restrict__ b,
                                             u16* __restrict__ xw) {
    int t = blockIdx.x * 4 + (threadIdx.x >> 6);
    int lane = threadIdx.x & 63;
    const float4 v = *(const float4*)(x + (size_t)t * 256 + lane * 4);
    float s = v.x + v.y + v.z + v.w;
    float s2 = v.x * v.x + v.y * v.y + v.z * v.z + v.w * v.w;
#pragma unroll
    for (int off = 1; off < 64; off <<= 1) {
        s += __shfl_xor(s, off);
        s2 += __shfl_xor(s2, off);
    }
    float mean = s * (1.0f / 256.0f);
    float var = s2 * (1.0f / 256.0f) - mean * mean;
    float rstd = 1.0f / sqrtf(var + 1e-5f);

    int bb = (t >= 50176) ? 1 : 0;
    int l = t - bb * 50176;
    int rr = l / 224, cc = l - rr * 224;
    int r2 = rr - 3; if (r2 < 0) r2 += 224;
    int c2 = cc - 3; if (c2 < 0) c2 += 224;
    int wi = r2 / 7, lr = r2 - wi * 7;
    int wj = c2 / 7, lc = c2 - wj * 7;
    size_t mIdx = (size_t)(((bb << 10) + wi * 32 + wj) * 49 + lr * 7 + lc);

    int ch = lane * 4;
    int hsel = ch >> 7, colb = ch & 127;
    const float4 gv = *(const float4*)(g + ch);
    const float4 bv = *(const float4*)(b + ch);
    union { uint2 u; u16 s4[4]; } pk;
    pk.s4[0] = f2bf((v.x - mean) * rstd * gv.x + bv.x);
    pk.s4[1] = f2bf((v.y - mean) * rstd * gv.y + bv.y);
    pk.s4[2] = f2bf((v.z - mean) * rstd * gv.z + bv.z);
    pk.s4[3] = f2bf((v.w - mean) * rstd * gv.w + bv.w);
    *(uint2*)(xw + (size_t)hsel * T_TOK * 128 + mIdx * 128 + colb) = pk.u;
}

// LN2: plain token order -> bf16
__global__ __launch_bounds__(256) void ln2_k(const float* __restrict__ x,
                                             const float* __restrict__ g,
                                             const float* __restrict__ b,
                                             u16* __restrict__ h) {
    int t = blockIdx.x * 4 + (threadIdx.x >> 6);
    int lane = threadIdx.x & 63;
    const float4 v = *(const float4*)(x + (size_t)t * 256 + lane * 4);
    float s = v.x + v.y + v.z + v.w;
    float s2 = v.x * v.x + v.y * v.y + v.z * v.z + v.w * v.w;
#pragma unroll
    for (int off = 1; off < 64; off <<= 1) {
        s += __shfl_xor(s, off);
        s2 += __shfl_xor(s2, off);
    }
    float mean = s * (1.0f / 256.0f);
    float var = s2 * (1.0f / 256.0f) - mean * mean;
    float rstd = 1.0f / sqrtf(var + 1e-5f);
    int ch = lane * 4;
    const float4 gv = *(const float4*)(g + ch);
    const float4 bv = *(const float4*)(b + ch);
    union { uint2 u; u16 s4[4]; } pk;
    pk.s4[0] = f2bf((v.x - mean) * rstd * gv.x + bv.x);
    pk.s4[1] = f2bf((v.y - mean) * rstd * gv.y + bv.y);
    pk.s4[2] = f2bf((v.z - mean) * rstd * gv.z + bv.z);
    pk.s4[3] = f2bf((v.w - mean) * rstd * gv.w + bv.w);
    *(uint2*)(h + (size_t)t * 256 + ch) = pk.u;
}

// ------------------------------------------------------- GEMM (128² tile) ----
// For qkv (N=384) and proj (N=128) whose N doesn't tile by 256.
// EPI: 0=qkv(store bf16, scale q cols), 1=proj(window-reverse+roll+residual->x2)
template <int EPI, int NBN>
__global__ __launch_bounds__(256) void gemm_k(const u16* __restrict__ A0,
                                              const u16* __restrict__ A1,
                                              const u16* __restrict__ W0,
                                              const u16* __restrict__ W1,
                                              const float* __restrict__ b0,
                                              const float* __restrict__ b1,
                                              const float* __restrict__ resid,
                                              void* __restrict__ outp,
                                              int K) {
    __shared__ u16 As[2][128][64];
    __shared__ u16 Bs[2][128][64];
    const int tid = threadIdx.x;
    const int lane = tid & 63;
    const int wave = tid >> 6;
    const int wr = wave >> 1, wc = wave & 1;
    const int id = blockIdx.x;
    const int v = (id & 7) * (gridDim.x >> 3) + (id >> 3);
    const int bm = v / NBN, bn = v - bm * NBN;
    const int hsel = blockIdx.z;
    const u16* A = hsel ? A1 : A0;
    const u16* W = hsel ? W1 : W0;
    const float* bias = hsel ? b1 : b0;
    const int r = lane & 15, kg = lane >> 4;
    const int wbase = wave * 64;

    f32x4 acc[4][4] = {};

    auto STAGE = [&](int buf, int kt) {
#pragma unroll
        for (int i = 0; i < 4; ++i) {
            int idx = i * 256 + tid;
            int row = idx >> 3;
            int cb = (idx & 7) ^ (row & 7);
            int ubase = (i * 256 + wbase) * 8;
            ld_g2l16(A + (size_t)(bm * 128 + row) * K + kt + cb * 8,
                     &As[buf][0][0] + ubase);
            ld_g2l16(W + (size_t)(bn * 128 + row) * K + kt + cb * 8,
                     &Bs[buf][0][0] + ubase);
        }
    };

    const int nk = K >> 6;
    STAGE(0, 0);
    __syncthreads();
    int cur = 0;
    for (int t = 0; t < nk; ++t) {
        if (t + 1 < nk) STAGE(cur ^ 1, (t + 1) << 6);
#pragma unroll
        for (int ks = 0; ks < 2; ++ks) {
            short8 fa[4], fb[4];
#pragma unroll
            for (int mf = 0; mf < 4; ++mf) {
                int ra = wr * 64 + mf * 16 + r;
                fa[mf] = *(const short8*)(&As[cur][ra][((ks * 4 + kg) ^ (ra & 7)) * 8]);
            }
#pragma unroll
            for (int nf = 0; nf < 4; ++nf) {
                int rb = wc * 64 + nf * 16 + r;
                fb[nf] = *(const short8*)(&Bs[cur][rb][((ks * 4 + kg) ^ (rb & 7)) * 8]);
            }
#pragma unroll
            for (int mf = 0; mf < 4; ++mf)
#pragma unroll
                for (int nf = 0; nf < 4; ++nf)
                    acc[mf][nf] = __builtin_amdgcn_mfma_f32_16x16x32_bf16(
                        fa[mf], fb[nf], acc[mf][nf], 0, 0, 0);
        }
        __syncthreads();
        cur ^= 1;
    }

#pragma unroll
    for (int mf = 0; mf < 4; ++mf) {
#pragma unroll
        for (int nf = 0; nf < 4; ++nf) {
#pragma unroll
            for (int j = 0; j < 4; ++j) {
                int row = wr * 64 + mf * 16 + kg * 4 + j;
                int col = wc * 64 + nf * 16 + r;
                int gm = bm * 128 + row;
                int gn = bn * 128 + col;
                float vv = acc[mf][nf][j] + bias[gn];
                if (EPI == 0) {
                    if (gn < 128) vv *= 0.17677669529663687f;  // 1/sqrt(32) on q
                    ((u16*)outp)[(size_t)hsel * T_TOK * 384 + (size_t)gm * 384 + gn] = f2bf(vv);
                } else {
                    int win = gm / 49, n = gm - win * 49;
                    int bb = win >> 10, w = win & 1023, wi = w >> 5, wj = w & 31;
                    int lr = n / 7, lc = n - lr * 7;
                    int R = wi * 7 + lr + 3;  if (R >= 224) R -= 224;
                    int Cc = wj * 7 + lc + 3; if (Cc >= 224) Cc -= 224;
                    size_t o = ((size_t)bb * 50176 + (size_t)R * 224 + Cc) * 256 +
                               hsel * 128 + gn;
                    ((float*)outp)[o] = resid[o] + vv;
                }
            }
        }
    }
}

// ------------------------------------------------------- GEMM (256² tile) ----
// For fc1/fc2: 512 threads = 8 waves (2M x 4N), wave tile 128x64, BK=32,
// LDS 64 KB double-buffered -> 2 blocks/CU (16 waves): the co-resident
// block's MFMA hides this block's per-K-step vmcnt(0) stage drain (m114
// implicit overlap). __launch_bounds__(512,4) = 4 waves/SIMD for 2 blocks.
// BK=32 swizzle: rows are 4x 16B-chunks; stage cb=(idx&3)^(row&3), read
// chunk kg^(row&3) -> 16-lane group covers all 32 banks exactly 2x (free).
// EPI: 2=fc1(fast-gelu->bf16), 3=fc2(+bias+residual->f32 out)
template <int EPI, int NBN>
__global__ __launch_bounds__(512, 4) void gemm256_k(const u16* __restrict__ A,
                                                    const u16* __restrict__ W,
                                                    const float* __restrict__ bias,
                                                    const float* __restrict__ resid,
                                                    void* __restrict__ outp,
                                                    int K) {
    __shared__ u16 As[2][256][32];
    __shared__ u16 Bs[2][256][32];
    const int tid = threadIdx.x;
    const int lane = tid & 63;
    const int wave = tid >> 6;          // 0..7
    const int wr = wave >> 2, wc = wave & 3;
    const int id = blockIdx.x;
    const int v = (id & 7) * (gridDim.x >> 3) + (id >> 3);
    const int bm = v / NBN, bn = v - bm * NBN;
    const int r = lane & 15, kg = lane >> 4;

    f32x4 acc[8][4] = {};

    auto STAGE = [&](int buf, int kt) {
#pragma unroll
        for (int i = 0; i < 2; ++i) {
            int idx = i * 512 + tid;          // 0..1023 : 256 rows x 4 chunks
            int row = idx >> 2;
            int cb = (idx & 3) ^ (row & 3);   // pre-swizzled source chunk
            int ubase = idx * 8;              // linear LDS dest (elems)
            ld_g2l16(A + (size_t)(bm * 256 + row) * K + kt + cb * 8,
                     &As[buf][0][0] + ubase);
            ld_g2l16(W + (size_t)(bn * 256 + row) * K + kt + cb * 8,
                     &Bs[buf][0][0] + ubase);
        }
    };

    const int nk = K >> 5;
    STAGE(0, 0);
    __syncthreads();
    int cur = 0;
    for (int t = 0; t < nk; ++t) {
        if (t + 1 < nk) STAGE(cur ^ 1, (t + 1) << 5);
        short8 fa[8], fb[4];
#pragma unroll
        for (int mf = 0; mf < 8; ++mf) {
            int ra = wr * 128 + mf * 16 + r;
            fa[mf] = *(const short8*)(&As[cur][ra][(kg ^ (ra & 3)) * 8]);
        }
#pragma unroll
        for (int nf = 0; nf < 4; ++nf) {
            int rb = wc * 64 + nf * 16 + r;
            fb[nf] = *(const short8*)(&Bs[cur][rb][(kg ^ (rb & 3)) * 8]);
        }
#pragma unroll
        for (int mf = 0; mf < 8; ++mf)
#pragma unroll
            for (int nf = 0; nf < 4; ++nf)
                acc[mf][nf] = __builtin_amdgcn_mfma_f32_16x16x32_bf16(
                    fa[mf], fb[nf], acc[mf][nf], 0, 0, 0);
        __syncthreads();
        cur ^= 1;
    }

#pragma unroll
    for (int mf = 0; mf < 8; ++mf) {
#pragma unroll
        for (int nf = 0; nf < 4; ++nf) {
#pragma unroll
            for (int j = 0; j < 4; ++j) {
                int gm = bm * 256 + wr * 128 + mf * 16 + kg * 4 + j;
                int gn = bn * 256 + wc * 64 + nf * 16 + r;
                float vv = acc[mf][nf][j] + bias[gn];
                if (EPI == 2) {
                    // fast GELU: x*sigmoid(1.59577*(x+0.044715 x^3))
                    float y = vv * (1.0f + 0.044715f * vv * vv);
                    float t = __expf(-1.59576912f * y);
                    float gl = vv * __builtin_amdgcn_rcpf(1.0f + t);
                    ((u16*)outp)[(size_t)gm * 1024 + gn] = f2bf(gl);
                } else {
                    size_t o = (size_t)gm * 256 + gn;
                    ((float*)outp)[o] = vv + resid[o];
                }
            }
        }
    }
}

// ------------------------------------------------------------ attention ----
// MFMA attention: block = (half, window), wave = head. S = Q K^T via 16 MFMA
// (49 padded to 64), bias+exp+rowsum in C-layout regs, P -> LDS (bf16, XOR
// chunk-swizzle), V staged transposed+swizzled (pad rows clamp-copied so
// padding stays finite; P=0 masks them), PV via 16 MFMA. Q/K fragments load
// straight from global (row-contiguous, L2-hot) — no LDS for QK^T.
__global__ __launch_bounds__(256) void attn_mfma_k(const u16* __restrict__ qkv,
                                                   const float* __restrict__ btbl,
                                                   u16* __restrict__ attnout) {
    __shared__ u16 P_lds[4][64 * 64];  // 32 KB, per-head [n][m] swizzled
    __shared__ u16 V_t[4][32 * 64];    // 16 KB, per-head [d][m] swizzled

    int bid = blockIdx.x;
    int hsel = bid >> 11;
    int win = bid & 2047;
    int w = win & 1023;
    int wtype = (((w >> 5) == 31) ? 2 : 0) + (((w & 31) == 31) ? 1 : 0);
    const u16* src = qkv + (size_t)hsel * T_TOK * 384 + (size_t)win * 49 * 384;
    int tid = threadIdx.x;

    // ---- stage V transposed+swizzled: V_t[h][d][swz(m)] (m padded via clamp) ----
    for (int c = tid; c < 1024; c += 256) {   // 64 m-rows x 16 d-chunks
        int m = c >> 4;
        int ms = m < 49 ? m : 48;
        int d0 = (c & 15) * 8;
        uint4 u = *(const uint4*)(src + ms * 384 + 256 + d0);
        const u16* us = (const u16*)&u;
        int mc = m >> 3, ml = m & 7;
#pragma unroll
        for (int i = 0; i < 8; ++i) {
            int d = d0 + i;
            int hh = d >> 5, dl = d & 31;
            V_t[hh][dl * 64 + ((mc ^ (dl & 7)) << 3) + ml] = us[i];
        }
    }

    const int h = tid >> 6, l = tid & 63;
    const int lr = l & 15, lg = l >> 4;

    // ---- QK^T: direct global fragment loads ----
    short8 qa[4], kb[4];
#pragma unroll
    for (int t = 0; t < 4; ++t) {
        int n = t * 16 + lr; int ns = n < 49 ? n : 48;
        qa[t] = *(const short8*)(src + ns * 384 + h * 32 + lg * 8);
        kb[t] = *(const short8*)(src + ns * 384 + 128 + h * 32 + lg * 8);
    }
    f32x4 S[4][4] = {};
#pragma unroll
    for (int ni = 0; ni < 4; ++ni)
#pragma unroll
        for (int mi = 0; mi < 4; ++mi)
            S[ni][mi] = __builtin_amdgcn_mfma_f32_16x16x32_bf16(
                qa[ni], kb[mi], S[ni][mi], 0, 0, 0);

    __syncthreads();   // V_t staged (P_lds is per-wave, no cross-wave hazard)

    // ---- bias + exp + row sums + P write (no-max softmax: logits bounded) ----
    const float* bias = btbl + ((size_t)((hsel * 4 + wtype) * 4 + h)) * 2401;
    float rs[4][4];
#pragma unroll
    for (int ni = 0; ni < 4; ++ni) {
#pragma unroll
        for (int j = 0; j < 4; ++j) {
            int n = ni * 16 + lg * 4 + j;
            int ns = n < 49 ? n : 48;
            float rsum = 0.0f;
#pragma unroll
            for (int mi = 0; mi < 4; ++mi) {
                int m = mi * 16 + lr;
                int msr = m < 49 ? m : 48;
                float bb = bias[ns * 49 + msr];
                bool valid = (n < 49) && (m < 49);
                float p = valid ? __expf(S[ni][mi][j] + bb) : 0.0f;
                rsum += p;
                int mc = m >> 3;
                P_lds[h][n * 64 + ((mc ^ (n & 7)) << 3) + (m & 7)] = f2bf(p);
            }
#pragma unroll
            for (int off = 1; off < 16; off <<= 1)
                rsum += __shfl_xor(rsum, off);
            rs[ni][j] = rsum;
        }
    }

    // ---- PV: P (A-frag from P_lds) x V (B-frag from V_t), K=64 in 2 steps ----
    f32x4 pv[4][2] = {};
#pragma unroll
    for (int ks = 0; ks < 2; ++ks) {
        int mc = ks * 4 + lg;
        short8 pa[4], vb[2];
#pragma unroll
        for (int ni = 0; ni < 4; ++ni) {
            int n = ni * 16 + lr;
            pa[ni] = *(const short8*)(&P_lds[h][n * 64 + ((mc ^ (n & 7)) << 3)]);
        }
#pragma unroll
        for (int di = 0; di < 2; ++di) {
            int d = di * 16 + lr;
            vb[di] = *(const short8*)(&V_t[h][d * 64 + ((mc ^ (d & 7)) << 3)]);
        }
#pragma unroll
        for (int ni = 0; ni < 4; ++ni)
#pragma unroll
            for (int di = 0; di < 2; ++di)
                pv[ni][di] = __builtin_amdgcn_mfma_f32_16x16x32_bf16(
                    pa[ni], vb[di], pv[ni][di], 0, 0, 0);
    }

    // ---- normalize + store (rows n < 49 only) ----
#pragma unroll
    for (int ni = 0; ni < 4; ++ni) {
#pragma unroll
        for (int j = 0; j < 4; ++j) {
            int n = ni * 16 + lg * 4 + j;
            if (n < 49) {
                float inv = 1.0f / rs[ni][j];
                u16* op = attnout + (size_t)hsel * T_TOK * 128 +
                          (size_t)(win * 49 + n) * 128 + h * 32;
#pragma unroll
                for (int di = 0; di < 2; ++di)
                    op[di * 16 + lr] = f2bf(pv[ni][di][j] * inv);
            }
        }
    }
}

// ---------------------------------------------------------------- launch ----
extern "C" void kernel_launch(void* const* d_in, const int* in_sizes, int n_in,
                              void* d_out, int out_size, void* d_ws, size_t ws_size,
                              hipStream_t stream) {
    (void)in_sizes; (void)n_in; (void)out_size; (void)ws_size;
    const float* x      = (const float*)d_in[0];
    const float* n1g    = (const float*)d_in[3];
    const float* n1b    = (const float*)d_in[4];
    const float* n2g    = (const float*)d_in[5];
    const float* n2b    = (const float*)d_in[6];
    const float* qkvw1  = (const float*)d_in[7];
    const float* qkvb1  = (const float*)d_in[8];
    const float* projw1 = (const float*)d_in[9];
    const float* projb1 = (const float*)d_in[10];
    const float* rpb1   = (const float*)d_in[11];
    const float* qkvw2  = (const float*)d_in[12];
    const float* qkvb2  = (const float*)d_in[13];
    const float* projw2 = (const float*)d_in[14];
    const float* projb2 = (const float*)d_in[15];
    const float* rpb2   = (const float*)d_in[16];
    const float* fc1w   = (const float*)d_in[17];
    const float* fc1b   = (const float*)d_in[18];
    const float* fc2w   = (const float*)d_in[19];
    const float* fc2b   = (const float*)d_in[20];
    float* out = (float*)d_out;

    // ---- workspace layout (total 361,279,616 B) ----
    char* ws = (char*)d_ws;
    u16* qkv_buf = (u16*)ws;
    u16* xw      = (u16*)(ws + 154140672LL);
    u16* hidden  = (u16*)ws;
    float* x2    = (float*)(ws + 205520896LL);
    u16* hbuf    = (u16*)(ws + 308281344LL);
    float* btbl  = (float*)(ws + 359661568LL);
    u16* wbf     = (u16*)(ws + 359968896LL);
    u16* qw0 = wbf;
    u16* qw1 = wbf + 49152;
    u16* pw0 = wbf + 98304;
    u16* pw1 = wbf + 114688;
    u16* f1w = wbf + 131072;
    u16* f2w = wbf + 393216;

    cvt_all_k<<<2560, 256, 0, stream>>>(qkvw1, qkvw2, projw1, projw2, fc1w, fc2w, wbf);
    bias_tbl_k<<<32, 256, 0, stream>>>(rpb1, rpb2, btbl);

    ln1_k<<<25088, 256, 0, stream>>>(x, n1g, n1b, xw);

    // qkv: M=100352 (784 bm), N=384 (3 bn), per half
    gemm_k<0, 3><<<dim3(2352, 1, 2), 256, 0, stream>>>(
        xw, xw + (size_t)T_TOK * 128, qw0, qw1, qkvb1, qkvb2, nullptr, qkv_buf, 128);

    attn_mfma_k<<<4096, 256, 0, stream>>>(qkv_buf, btbl, xw);  // attnout -> xw

    // proj: N=128 (1 bn), per half
    gemm_k<1, 1><<<dim3(784, 1, 2), 256, 0, stream>>>(
        xw, xw + (size_t)T_TOK * 128, pw0, pw1, projb1, projb2, x, x2, 128);

    ln2_k<<<25088, 256, 0, stream>>>(x2, n2g, n2b, hbuf);
    // fc1 (256² tile, BK=32): M=100352 (392 bm), N=1024 (4 bn)
    gemm256_k<2, 4><<<1568, 512, 0, stream>>>(hbuf, f1w, fc1b, nullptr, hidden, 256);
    // fc2 (256² tile, BK=32): M=100352 (392 bm), N=256 (1 bn)
    gemm256_k<3, 1><<<392, 512, 0, stream>>>(hidden, f2w, fc2b, x2, out, 1024);
}

// Round 12
// 653.038 us; speedup vs baseline: 1.9127x; 1.9127x over previous
//
#include <hip/hip_runtime.h>

using u16 = unsigned short;
typedef short short8 __attribute__((ext_vector_type(8)));
typedef float f32x4 __attribute__((ext_vector_type(4)));

#define T_TOK 100352

__device__ __forceinline__ float bf2f(u16 u) {
    return __uint_as_float(((unsigned int)u) << 16);
}
__device__ __forceinline__ u16 f2bf(float f) {
    unsigned int u = __float_as_uint(f);
    u += 0x7fffu + ((u >> 16) & 1u);   // round-to-nearest-even
    return (u16)(u >> 16);
}

// async global->LDS, 16B per lane; LDS dest = wave-uniform base + lane*16
__device__ __forceinline__ void ld_g2l16(const u16* g, u16* l) {
    __builtin_amdgcn_global_load_lds((const __attribute__((address_space(1))) void*)g,
                                     (__attribute__((address_space(3))) void*)l,
                                     16, 0, 0);
}

// ---------------------------------------------------------------- setup ----
// all six weight matrices -> bf16 in one launch (contiguous dst arena)
__global__ __launch_bounds__(256) void cvt_all_k(const float* __restrict__ q1,
                                                 const float* __restrict__ q2,
                                                 const float* __restrict__ p1,
                                                 const float* __restrict__ p2,
                                                 const float* __restrict__ f1,
                                                 const float* __restrict__ f2,
                                                 u16* __restrict__ dst) {
    int i = blockIdx.x * 256 + threadIdx.x;
    if (i >= 655360) return;
    const float* s; int off;
    if (i < 49152)       { s = q1; off = 0; }
    else if (i < 98304)  { s = q2; off = 49152; }
    else if (i < 114688) { s = p1; off = 98304; }
    else if (i < 131072) { s = p2; off = 114688; }
    else if (i < 393216) { s = f1; off = 131072; }
    else                 { s = f2; off = 393216; }
    dst[i] = f2bf(s[i - off]);
}

// bias table: [half(2)][wtype(4)][head(4)][n(49)][m(49)] f32
// wtype = (wi==31)*2 + (wj==31)
__global__ __launch_bounds__(256) void bias_tbl_k(const float* __restrict__ rpb0,
                                                  const float* __restrict__ rpb1,
                                                  float* __restrict__ tbl) {
    int id = blockIdx.x;               // half*16 + wtype*4 + h
    int hsel = id >> 4, wtype = (id >> 2) & 3, h = id & 3;
    const float* rpb = hsel ? rpb1 : rpb0;
    int redge = wtype >> 1, cedge = wtype & 1;
    float* o = tbl + (size_t)id * 2401;
    for (int i = threadIdx.x; i < 2401; i += 256) {
        int n = i / 49, m = i - n * 49;
        int rn = n / 7, cn = n - rn * 7, rm = m / 7, cm = m - rm * 7;
        int rpi = (rn - rm + 6) * 13 + (cn - cm + 6);
        float v = rpb[rpi * 4 + h];
        // shifted-window mask (regions only differ on edge windows)
        int grn = redge ? (rn < 4 ? 1 : 2) : 0;
        int grm = redge ? (rm < 4 ? 1 : 2) : 0;
        int gcn = cedge ? (cn < 4 ? 1 : 2) : 0;
        int gcm = cedge ? (cm < 4 ? 1 : 2) : 0;
        if ((grn * 3 + gcn) != (grm * 3 + gcm)) v += -100.0f;
        // physical cone mask (derived allowed sets, fp32-borderline (5,6) IN)
        int dr = rn - rm, dc = cn - cm;
        bool ok;
        if (n == m) ok = true;
        else if (hsel == 0)
            ok = (dc == 1 && dr == 1) || (dc == 2 && dr == 2) ||
                 (dc == 3 && (dr == 3 || dr == 4)) ||
                 (dc == 4 && (dr == 4 || dr == 5)) ||
                 (dc == 5 && (dr == 5 || dr == 6)) ||
                 (dc == 6 && (dr == 5 || dr == 6));
        else
            ok = (dr == -1 && dc >= 3 && dc <= 6) || (dr == -2 && dc == 6);
        if (!ok) v += -100.0f;
        o[i] = v;
    }
}

// ------------------------------------------------------------ layernorms ----
// LN1 + roll(-3,-3) + window partition -> bf16 windowed layout, both halves
__global__ __launch_bounds__(256) void ln1_k(const float* __restrict__ x,
                                             const float* __restrict__ g,
                                             const float* __restrict__ b,
                                             u16* __restrict__ xw) {
    int t = blockIdx.x * 4 + (threadIdx.x >> 6);
    int lane = threadIdx.x & 63;
    const float4 v = *(const float4*)(x + (size_t)t * 256 + lane * 4);
    float s = v.x + v.y + v.z + v.w;
    float s2 = v.x * v.x + v.y * v.y + v.z * v.z + v.w * v.w;
#pragma unroll
    for (int off = 1; off < 64; off <<= 1) {
        s += __shfl_xor(s, off);
        s2 += __shfl_xor(s2, off);
    }
    float mean = s * (1.0f / 256.0f);
    float var = s2 * (1.0f / 256.0f) - mean * mean;
    float rstd = 1.0f / sqrtf(var + 1e-5f);

    int bb = (t >= 50176) ? 1 : 0;
    int l = t - bb * 50176;
    int rr = l / 224, cc = l - rr * 224;
    int r2 = rr - 3; if (r2 < 0) r2 += 224;
    int c2 = cc - 3; if (c2 < 0) c2 += 224;
    int wi = r2 / 7, lr = r2 - wi * 7;
    int wj = c2 / 7, lc = c2 - wj * 7;
    size_t mIdx = (size_t)(((bb << 10) + wi * 32 + wj) * 49 + lr * 7 + lc);

    int ch = lane * 4;
    int hsel = ch >> 7, colb = ch & 127;
    const float4 gv = *(const float4*)(g + ch);
    const float4 bv = *(const float4*)(b + ch);
    union { uint2 u; u16 s4[4]; } pk;
    pk.s4[0] = f2bf((v.x - mean) * rstd * gv.x + bv.x);
    pk.s4[1] = f2bf((v.y - mean) * rstd * gv.y + bv.y);
    pk.s4[2] = f2bf((v.z - mean) * rstd * gv.z + bv.z);
    pk.s4[3] = f2bf((v.w - mean) * rstd * gv.w + bv.w);
    *(uint2*)(xw + (size_t)hsel * T_TOK * 128 + mIdx * 128 + colb) = pk.u;
}

// LN2: plain token order -> bf16
__global__ __launch_bounds__(256) void ln2_k(const float* __restrict__ x,
                                             const float* __restrict__ g,
                                             const float* __restrict__ b,
                                             u16* __restrict__ h) {
    int t = blockIdx.x * 4 + (threadIdx.x >> 6);
    int lane = threadIdx.x & 63;
    const float4 v = *(const float4*)(x + (size_t)t * 256 + lane * 4);
    float s = v.x + v.y + v.z + v.w;
    float s2 = v.x * v.x + v.y * v.y + v.z * v.z + v.w * v.w;
#pragma unroll
    for (int off = 1; off < 64; off <<= 1) {
        s += __shfl_xor(s, off);
        s2 += __shfl_xor(s2, off);
    }
    float mean = s * (1.0f / 256.0f);
    float var = s2 * (1.0f / 256.0f) - mean * mean;
    float rstd = 1.0f / sqrtf(var + 1e-5f);
    int ch = lane * 4;
    const float4 gv = *(const float4*)(g + ch);
    const float4 bv = *(const float4*)(b + ch);
    union { uint2 u; u16 s4[4]; } pk;
    pk.s4[0] = f2bf((v.x - mean) * rstd * gv.x + bv.x);
    pk.s4[1] = f2bf((v.y - mean) * rstd * gv.y + bv.y);
    pk.s4[2] = f2bf((v.z - mean) * rstd * gv.z + bv.z);
    pk.s4[3] = f2bf((v.w - mean) * rstd * gv.w + bv.w);
    *(uint2*)(h + (size_t)t * 256 + ch) = pk.u;
}

// ------------------------------------------------------- GEMM (128² tile) ----
// For qkv (N=384) and proj (N=128) whose N doesn't tile by 256.
// EPI: 0=qkv(store bf16, scale q cols), 1=proj(window-reverse+roll+residual->x2)
template <int EPI, int NBN>
__global__ __launch_bounds__(256) void gemm_k(const u16* __restrict__ A0,
                                              const u16* __restrict__ A1,
                                              const u16* __restrict__ W0,
                                              const u16* __restrict__ W1,
                                              const float* __restrict__ b0,
                                              const float* __restrict__ b1,
                                              const float* __restrict__ resid,
                                              void* __restrict__ outp,
                                              int K) {
    __shared__ u16 As[2][128][64];
    __shared__ u16 Bs[2][128][64];
    const int tid = threadIdx.x;
    const int lane = tid & 63;
    const int wave = tid >> 6;
    const int wr = wave >> 1, wc = wave & 1;
    const int id = blockIdx.x;
    const int v = (id & 7) * (gridDim.x >> 3) + (id >> 3);
    const int bm = v / NBN, bn = v - bm * NBN;
    const int hsel = blockIdx.z;
    const u16* A = hsel ? A1 : A0;
    const u16* W = hsel ? W1 : W0;
    const float* bias = hsel ? b1 : b0;
    const int r = lane & 15, kg = lane >> 4;
    const int wbase = wave * 64;

    f32x4 acc[4][4] = {};

    auto STAGE = [&](int buf, int kt) {
#pragma unroll
        for (int i = 0; i < 4; ++i) {
            int idx = i * 256 + tid;
            int row = idx >> 3;
            int cb = (idx & 7) ^ (row & 7);
            int ubase = (i * 256 + wbase) * 8;
            ld_g2l16(A + (size_t)(bm * 128 + row) * K + kt + cb * 8,
                     &As[buf][0][0] + ubase);
            ld_g2l16(W + (size_t)(bn * 128 + row) * K + kt + cb * 8,
                     &Bs[buf][0][0] + ubase);
        }
    };

    const int nk = K >> 6;
    STAGE(0, 0);
    __syncthreads();
    int cur = 0;
    for (int t = 0; t < nk; ++t) {
        if (t + 1 < nk) STAGE(cur ^ 1, (t + 1) << 6);
#pragma unroll
        for (int ks = 0; ks < 2; ++ks) {
            short8 fa[4], fb[4];
#pragma unroll
            for (int mf = 0; mf < 4; ++mf) {
                int ra = wr * 64 + mf * 16 + r;
                fa[mf] = *(const short8*)(&As[cur][ra][((ks * 4 + kg) ^ (ra & 7)) * 8]);
            }
#pragma unroll
            for (int nf = 0; nf < 4; ++nf) {
                int rb = wc * 64 + nf * 16 + r;
                fb[nf] = *(const short8*)(&Bs[cur][rb][((ks * 4 + kg) ^ (rb & 7)) * 8]);
            }
#pragma unroll
            for (int mf = 0; mf < 4; ++mf)
#pragma unroll
                for (int nf = 0; nf < 4; ++nf)
                    acc[mf][nf] = __builtin_amdgcn_mfma_f32_16x16x32_bf16(
                        fa[mf], fb[nf], acc[mf][nf], 0, 0, 0);
        }
        __syncthreads();
        cur ^= 1;
    }

#pragma unroll
    for (int mf = 0; mf < 4; ++mf) {
#pragma unroll
        for (int nf = 0; nf < 4; ++nf) {
#pragma unroll
            for (int j = 0; j < 4; ++j) {
                int row = wr * 64 + mf * 16 + kg * 4 + j;
                int col = wc * 64 + nf * 16 + r;
                int gm = bm * 128 + row;
                int gn = bn * 128 + col;
                float vv = acc[mf][nf][j] + bias[gn];
                if (EPI == 0) {
                    if (gn < 128) vv *= 0.17677669529663687f;  // 1/sqrt(32) on q
                    ((u16*)outp)[(size_t)hsel * T_TOK * 384 + (size_t)gm * 384 + gn] = f2bf(vv);
                } else {
                    int win = gm / 49, n = gm - win * 49;
                    int bb = win >> 10, w = win & 1023, wi = w >> 5, wj = w & 31;
                    int lr = n / 7, lc = n - lr * 7;
                    int R = wi * 7 + lr + 3;  if (R >= 224) R -= 224;
                    int Cc = wj * 7 + lc + 3; if (Cc >= 224) Cc -= 224;
                    size_t o = ((size_t)bb * 50176 + (size_t)R * 224 + Cc) * 256 +
                               hsel * 128 + gn;
                    ((float*)outp)[o] = resid[o] + vv;
                }
            }
        }
    }
}

// ---------------------------------------------- GEMM (128x256 tile, BK=32) ----
// For fc1/fc2. 512 threads = 8 waves (2M x 4N), wave tile 64x64 -> acc 64 f32
// (+ ~50 other regs ~= 115 total, fits the 128-reg cap of 4 waves/SIMD without
// spill — R11's failure mode was the 128x64 wave tile's 176-reg need under the
// same cap). LDS 48 KB dbuf -> 2 blocks/CU (16 waves): co-resident block's
// MFMA hides the per-K-step stage drain (m114). BK=32 swizzle for 64B rows:
// cb = ch ^ ((row>>1)&3) -> exactly 2-way bank aliasing on ds_read_b128 (free,
// m136); R11's ^(row&3) was 4-way because 64B rows have bank-period 2.
// EPI: 2=fc1(fast-gelu->bf16), 3=fc2(+bias+residual->f32 out)
template <int EPI, int NBN>
__global__ __launch_bounds__(512, 4) void gemm256_k(const u16* __restrict__ A,
                                                    const u16* __restrict__ W,
                                                    const float* __restrict__ bias,
                                                    const float* __restrict__ resid,
                                                    void* __restrict__ outp,
                                                    int K) {
    __shared__ u16 As[2][128][32];   //  8 KB per buf
    __shared__ u16 Bs[2][256][32];   // 16 KB per buf
    const int tid = threadIdx.x;
    const int lane = tid & 63;
    const int wave = tid >> 6;          // 0..7
    const int wr = wave >> 2, wc = wave & 3;   // 2M x 4N
    const int id = blockIdx.x;
    const int v = (id & 7) * (gridDim.x >> 3) + (id >> 3);
    const int bm = v / NBN, bn = v - bm * NBN;
    const int r = lane & 15, kg = lane >> 4;

    f32x4 acc[4][4] = {};

    auto STAGE = [&](int buf, int kt) {
        {   // A: 128 rows x 4 16B-chunks = 512 loads (1/thread)
            int row = tid >> 2, ch = tid & 3;
            int cb = ch ^ ((row >> 1) & 3);
            ld_g2l16(A + (size_t)(bm * 128 + row) * K + kt + cb * 8,
                     &As[buf][0][0] + tid * 8);
        }
#pragma unroll
        for (int i = 0; i < 2; ++i) {   // B: 256 rows x 4 chunks = 1024 loads
            int idx = i * 512 + tid;
            int row = idx >> 2, ch = idx & 3;
            int cb = ch ^ ((row >> 1) & 3);
            ld_g2l16(W + (size_t)(bn * 256 + row) * K + kt + cb * 8,
                     &Bs[buf][0][0] + idx * 8);
        }
    };

    const int nk = K >> 5;
    STAGE(0, 0);
    __syncthreads();
    int cur = 0;
    for (int t = 0; t < nk; ++t) {
        if (t + 1 < nk) STAGE(cur ^ 1, (t + 1) << 5);
        short8 fa[4], fb[4];
#pragma unroll
        for (int mf = 0; mf < 4; ++mf) {
            int ra = wr * 64 + mf * 16 + r;
            fa[mf] = *(const short8*)(&As[cur][ra][(kg ^ ((ra >> 1) & 3)) * 8]);
        }
#pragma unroll
        for (int nf = 0; nf < 4; ++nf) {
            int rb = wc * 64 + nf * 16 + r;
            fb[nf] = *(const short8*)(&Bs[cur][rb][(kg ^ ((rb >> 1) & 3)) * 8]);
        }
#pragma unroll
        for (int mf = 0; mf < 4; ++mf)
#pragma unroll
            for (int nf = 0; nf < 4; ++nf)
                acc[mf][nf] = __builtin_amdgcn_mfma_f32_16x16x32_bf16(
                    fa[mf], fb[nf], acc[mf][nf], 0, 0, 0);
        __syncthreads();
        cur ^= 1;
    }

#pragma unroll
    for (int mf = 0; mf < 4; ++mf) {
#pragma unroll
        for (int nf = 0; nf < 4; ++nf) {
#pragma unroll
            for (int j = 0; j < 4; ++j) {
                int gm = bm * 128 + wr * 64 + mf * 16 + kg * 4 + j;
                int gn = bn * 256 + wc * 64 + nf * 16 + r;
                float vv = acc[mf][nf][j] + bias[gn];
                if (EPI == 2) {
                    // fast GELU: x*sigmoid(1.59577*(x+0.044715 x^3))
                    float y = vv * (1.0f + 0.044715f * vv * vv);
                    float t = __expf(-1.59576912f * y);
                    float gl = vv * __builtin_amdgcn_rcpf(1.0f + t);
                    ((u16*)outp)[(size_t)gm * 1024 + gn] = f2bf(gl);
                } else {
                    size_t o = (size_t)gm * 256 + gn;
                    ((float*)outp)[o] = vv + resid[o];
                }
            }
        }
    }
}

// ------------------------------------------------------------ attention ----
// MFMA attention: block = (half, window), wave = head. S = Q K^T via 16 MFMA
// (49 padded to 64), bias+exp+rowsum in C-layout regs, P -> LDS (bf16, XOR
// chunk-swizzle), V staged transposed+swizzled (pad rows clamp-copied so
// padding stays finite; P=0 masks them), PV via 16 MFMA. Q/K fragments load
// straight from global (row-contiguous, L2-hot) — no LDS for QK^T.
__global__ __launch_bounds__(256) void attn_mfma_k(const u16* __restrict__ qkv,
                                                   const float* __restrict__ btbl,
                                                   u16* __restrict__ attnout) {
    __shared__ u16 P_lds[4][64 * 64];  // 32 KB, per-head [n][m] swizzled
    __shared__ u16 V_t[4][32 * 64];    // 16 KB, per-head [d][m] swizzled

    int bid = blockIdx.x;
    int hsel = bid >> 11;
    int win = bid & 2047;
    int w = win & 1023;
    int wtype = (((w >> 5) == 31) ? 2 : 0) + (((w & 31) == 31) ? 1 : 0);
    const u16* src = qkv + (size_t)hsel * T_TOK * 384 + (size_t)win * 49 * 384;
    int tid = threadIdx.x;

    // ---- stage V transposed+swizzled: V_t[h][d][swz(m)] (m padded via clamp) ----
    for (int c = tid; c < 1024; c += 256) {   // 64 m-rows x 16 d-chunks
        int m = c >> 4;
        int ms = m < 49 ? m : 48;
        int d0 = (c & 15) * 8;
        uint4 u = *(const uint4*)(src + ms * 384 + 256 + d0);
        const u16* us = (const u16*)&u;
        int mc = m >> 3, ml = m & 7;
#pragma unroll
        for (int i = 0; i < 8; ++i) {
            int d = d0 + i;
            int hh = d >> 5, dl = d & 31;
            V_t[hh][dl * 64 + ((mc ^ (dl & 7)) << 3) + ml] = us[i];
        }
    }

    const int h = tid >> 6, l = tid & 63;
    const int lr = l & 15, lg = l >> 4;

    // ---- QK^T: direct global fragment loads ----
    short8 qa[4], kb[4];
#pragma unroll
    for (int t = 0; t < 4; ++t) {
        int n = t * 16 + lr; int ns = n < 49 ? n : 48;
        qa[t] = *(const short8*)(src + ns * 384 + h * 32 + lg * 8);
        kb[t] = *(const short8*)(src + ns * 384 + 128 + h * 32 + lg * 8);
    }
    f32x4 S[4][4] = {};
#pragma unroll
    for (int ni = 0; ni < 4; ++ni)
#pragma unroll
        for (int mi = 0; mi < 4; ++mi)
            S[ni][mi] = __builtin_amdgcn_mfma_f32_16x16x32_bf16(
                qa[ni], kb[mi], S[ni][mi], 0, 0, 0);

    __syncthreads();   // V_t staged (P_lds is per-wave, no cross-wave hazard)

    // ---- bias + exp + row sums + P write (no-max softmax: logits bounded) ----
    const float* bias = btbl + ((size_t)((hsel * 4 + wtype) * 4 + h)) * 2401;
    float rs[4][4];
#pragma unroll
    for (int ni = 0; ni < 4; ++ni) {
#pragma unroll
        for (int j = 0; j < 4; ++j) {
            int n = ni * 16 + lg * 4 + j;
            int ns = n < 49 ? n : 48;
            float rsum = 0.0f;
#pragma unroll
            for (int mi = 0; mi < 4; ++mi) {
                int m = mi * 16 + lr;
                int msr = m < 49 ? m : 48;
                float bb = bias[ns * 49 + msr];
                bool valid = (n < 49) && (m < 49);
                float p = valid ? __expf(S[ni][mi][j] + bb) : 0.0f;
                rsum += p;
                int mc = m >> 3;
                P_lds[h][n * 64 + ((mc ^ (n & 7)) << 3) + (m & 7)] = f2bf(p);
            }
#pragma unroll
            for (int off = 1; off < 16; off <<= 1)
                rsum += __shfl_xor(rsum, off);
            rs[ni][j] = rsum;
        }
    }

    // ---- PV: P (A-frag from P_lds) x V (B-frag from V_t), K=64 in 2 steps ----
    f32x4 pv[4][2] = {};
#pragma unroll
    for (int ks = 0; ks < 2; ++ks) {
        int mc = ks * 4 + lg;
        short8 pa[4], vb[2];
#pragma unroll
        for (int ni = 0; ni < 4; ++ni) {
            int n = ni * 16 + lr;
            pa[ni] = *(const short8*)(&P_lds[h][n * 64 + ((mc ^ (n & 7)) << 3)]);
        }
#pragma unroll
        for (int di = 0; di < 2; ++di) {
            int d = di * 16 + lr;
            vb[di] = *(const short8*)(&V_t[h][d * 64 + ((mc ^ (d & 7)) << 3)]);
        }
#pragma unroll
        for (int ni = 0; ni < 4; ++ni)
#pragma unroll
            for (int di = 0; di < 2; ++di)
                pv[ni][di] = __builtin_amdgcn_mfma_f32_16x16x32_bf16(
                    pa[ni], vb[di], pv[ni][di], 0, 0, 0);
    }

    // ---- normalize + store (rows n < 49 only) ----
#pragma unroll
    for (int ni = 0; ni < 4; ++ni) {
#pragma unroll
        for (int j = 0; j < 4; ++j) {
            int n = ni * 16 + lg * 4 + j;
            if (n < 49) {
                float inv = 1.0f / rs[ni][j];
                u16* op = attnout + (size_t)hsel * T_TOK * 128 +
                          (size_t)(win * 49 + n) * 128 + h * 32;
#pragma unroll
                for (int di = 0; di < 2; ++di)
                    op[di * 16 + lr] = f2bf(pv[ni][di][j] * inv);
            }
        }
    }
}

// ---------------------------------------------------------------- launch ----
extern "C" void kernel_launch(void* const* d_in, const int* in_sizes, int n_in,
                              void* d_out, int out_size, void* d_ws, size_t ws_size,
                              hipStream_t stream) {
    (void)in_sizes; (void)n_in; (void)out_size; (void)ws_size;
    const float* x      = (const float*)d_in[0];
    const float* n1g    = (const float*)d_in[3];
    const float* n1b    = (const float*)d_in[4];
    const float* n2g    = (const float*)d_in[5];
    const float* n2b    = (const float*)d_in[6];
    const float* qkvw1  = (const float*)d_in[7];
    const float* qkvb1  = (const float*)d_in[8];
    const float* projw1 = (const float*)d_in[9];
    const float* projb1 = (const float*)d_in[10];
    const float* rpb1   = (const float*)d_in[11];
    const float* qkvw2  = (const float*)d_in[12];
    const float* qkvb2  = (const float*)d_in[13];
    const float* projw2 = (const float*)d_in[14];
    const float* projb2 = (const float*)d_in[15];
    const float* rpb2   = (const float*)d_in[16];
    const float* fc1w   = (const float*)d_in[17];
    const float* fc1b   = (const float*)d_in[18];
    const float* fc2w   = (const float*)d_in[19];
    const float* fc2b   = (const float*)d_in[20];
    float* out = (float*)d_out;

    // ---- workspace layout (total 361,279,616 B) ----
    char* ws = (char*)d_ws;
    u16* qkv_buf = (u16*)ws;
    u16* xw      = (u16*)(ws + 154140672LL);
    u16* hidden  = (u16*)ws;
    float* x2    = (float*)(ws + 205520896LL);
    u16* hbuf    = (u16*)(ws + 308281344LL);
    float* btbl  = (float*)(ws + 359661568LL);
    u16* wbf     = (u16*)(ws + 359968896LL);
    u16* qw0 = wbf;
    u16* qw1 = wbf + 49152;
    u16* pw0 = wbf + 98304;
    u16* pw1 = wbf + 114688;
    u16* f1w = wbf + 131072;
    u16* f2w = wbf + 393216;

    cvt_all_k<<<2560, 256, 0, stream>>>(qkvw1, qkvw2, projw1, projw2, fc1w, fc2w, wbf);
    bias_tbl_k<<<32, 256, 0, stream>>>(rpb1, rpb2, btbl);

    ln1_k<<<25088, 256, 0, stream>>>(x, n1g, n1b, xw);

    // qkv: M=100352 (784 bm), N=384 (3 bn), per half
    gemm_k<0, 3><<<dim3(2352, 1, 2), 256, 0, stream>>>(
        xw, xw + (size_t)T_TOK * 128, qw0, qw1, qkvb1, qkvb2, nullptr, qkv_buf, 128);

    attn_mfma_k<<<4096, 256, 0, stream>>>(qkv_buf, btbl, xw);  // attnout -> xw

    // proj: N=128 (1 bn), per half
    gemm_k<1, 1><<<dim3(784, 1, 2), 256, 0, stream>>>(
        xw, xw + (size_t)T_TOK * 128, pw0, pw1, projb1, projb2, x, x2, 128);

    ln2_k<<<25088, 256, 0, stream>>>(x2, n2g, n2b, hbuf);
    // fc1 (128x256 tile, BK=32): M=100352 (784 bm), N=1024 (4 bn)
    gemm256_k<2, 4><<<3136, 512, 0, stream>>>(hbuf, f1w, fc1b, nullptr, hidden, 256);
    // fc2 (128x256 tile, BK=32): M=100352 (784 bm), N=256 (1 bn)
    gemm256_k<3, 1><<<784, 512, 0, stream>>>(hidden, f2w, fc2b, x2, out, 1024);
}